// Round 7
// baseline (296.717 us; speedup 1.0000x reference)
//
#include <hip/hip_runtime.h>

typedef __attribute__((ext_vector_type(8))) short short8;
typedef __attribute__((ext_vector_type(4))) float f32x4;
typedef __attribute__((ext_vector_type(16))) float f32x16;
typedef unsigned int u32;
typedef __attribute__((ext_vector_type(4))) u32 u32x4;
typedef unsigned short u16;

#define DEV __device__ __forceinline__

DEV void async16(const void* g, void* l) {
  __builtin_amdgcn_global_load_lds((const __attribute__((address_space(1))) u32*)g,
                                   (__attribute__((address_space(3))) u32*)l, 16, 0, 0);
}

DEV u16 f2bf(float f) {
  u32 u = __builtin_bit_cast(u32, f);
  u32 r = (u + 0x7FFFu + ((u >> 16) & 1u)) >> 16;
  return (u16)r;
}
DEV float bf2f(u16 h) { return __builtin_bit_cast(float, (u32)h << 16); }

DEV u32 cvtpk(float lo, float hi) {  // packs {bf16(lo), bf16(hi)} -> u32 (lo in low16)
  u32 r;
  asm("v_cvt_pk_bf16_f32 %0, %1, %2" : "=v"(r) : "v"(lo), "v"(hi));
  return r;
}

#define RAW_BARRIER() asm volatile("s_barrier" ::: "memory")
#define VMWAIT(N) asm volatile("s_waitcnt vmcnt(" #N ")" ::: "memory")

// ---------------- fused cast f32 -> bf16 of x + 4 weights (dst regions contiguous) --
__global__ void cast_all_kernel(const float* __restrict__ x, const float* __restrict__ wq,
                                const float* __restrict__ wk, const float* __restrict__ wv,
                                const float* __restrict__ wo, u16* __restrict__ out) {
  constexpr int XN = 2097152;  // x float4 count (4096*2048/4)
  constexpr int WN = 1048576;  // each weight float4 count
  constexpr int TOT = XN + 4 * WN;
  int stride = gridDim.x * blockDim.x;
  for (int i = blockIdx.x * blockDim.x + threadIdx.x; i < TOT; i += stride) {
    const float* src;
    int off;
    if (i < XN) {
      src = x; off = i;
    } else {
      int j = i - XN, wsel = j >> 20;
      const float* ws4[4] = {wq, wk, wv, wo};
      src = ws4[wsel]; off = j & (WN - 1);
    }
    float4 v = reinterpret_cast<const float4*>(src)[off];
    ushort4 o = make_ushort4(f2bf(v.x), f2bf(v.y), f2bf(v.z), f2bf(v.w));
    reinterpret_cast<ushort4*>(out)[i] = o;
  }
}

// ---------------- 8-phase 256^2 fused QKV GEMM (+RoPE epilogue) ----------------
// C[M=4096][N=6144] = A[M][K=2048] * B[N][K]^T, bf16 in, f32 acc.
// 384 blocks x 512 thr (8 waves: wm=w>>2 in 2 M-halves, wn=w&3 in 4 N-strips of 32).
// K-tiles of 64, 2x64KB LDS dbuf. Phase p computes quadrant (h_A=p>>1, h_B=p&1);
// A/B frags register-reused across phase pairs. Chunk issue order A0,B0,B1,A1 with
// counted vmcnt(4) (never 0 in-loop), raw s_barrier (no compiler vmcnt0 drain).
// Epilogue: Q/K get RoPE (pair via lane^1 shfl, f32) + Q scaled log2e/sqrt(128);
// Q/K -> [B,H,S,HD], V -> [B,H,HD,S] (transposed).
__global__ __launch_bounds__(512, 2) void gemm_qkv8(const u16* __restrict__ A,
                                                    const u16* __restrict__ Bw,
                                                    u16* __restrict__ q_ws,
                                                    u16* __restrict__ k_ws,
                                                    u16* __restrict__ vt_ws,
                                                    const float* __restrict__ cbp,
                                                    const float* __restrict__ sbp) {
  constexpr int K = 2048, NT = 32;
  __shared__ char sm[131072];  // buf b @ b*65536: A[256][64]sw @0, B[256][64]sw @32768
  const int tid = threadIdx.x, lane = tid & 63, w = tid >> 6;
  const int wm = w >> 2, wn = w & 3;
  const int bid = blockIdx.x;
  const int n = (bid & 7) * 48 + (bid >> 3);  // bijective XCD swizzle (384 = 8*48)
  const int row0 = (n & 15) * 256, col0 = (n >> 4) * 256;

  f32x4 acc[2][2][4][2] = {};

  // chunk: 0=A-half0, 1=B-half0, 2=B-half1, 3=A-half1 (each 128 rows x 64 cols bf16)
  auto stage_chunk = [&](int bufoff, int chunk, int k0) {
    const bool isA = (chunk == 0) || (chunk == 3);
    const u16* src = isA ? A : Bw;
    const int h = isA ? ((chunk == 3) ? 1 : 0) : (chunk - 1);
    const int rbase = (isA ? row0 : col0) + h * 128;
    const int ldsbase = bufoff + (isA ? 0 : 32768) + h * 16384;
#pragma unroll
    for (int i = 0; i < 2; ++i) {
      int slot = tid + i * 512;
      int r = slot >> 3, cs = slot & 7;
      async16(src + (size_t)(rbase + r) * K + k0 + ((cs ^ (r & 7)) << 3),
              sm + ldsbase + slot * 16);
    }
  };

  short8 af[4][2], bf0[2][2], bf1[2][2];
  auto ldA = [&](int base, int ha) {
#pragma unroll
    for (int mi = 0; mi < 4; ++mi) {
      int row = ha * 128 + wm * 64 + mi * 16 + (lane & 15);
#pragma unroll
      for (int kk = 0; kk < 2; ++kk)
        af[mi][kk] = *reinterpret_cast<const short8*>(
            sm + base + row * 128 + ((((kk << 2) + (lane >> 4)) ^ (row & 7)) << 4));
    }
  };
  auto ldB = [&](short8 (&bf)[2][2], int base, int hb) {
#pragma unroll
    for (int ni = 0; ni < 2; ++ni) {
      int row = hb * 128 + wn * 32 + ni * 16 + (lane & 15);
#pragma unroll
      for (int kk = 0; kk < 2; ++kk)
        bf[ni][kk] = *reinterpret_cast<const short8*>(
            sm + base + 32768 + row * 128 + ((((kk << 2) + (lane >> 4)) ^ (row & 7)) << 4));
    }
  };

#define MFMA16(HA, HB, BF)                                                              \
  __builtin_amdgcn_s_setprio(1);                                                        \
  _Pragma("unroll") for (int mi = 0; mi < 4; ++mi)                                      \
      _Pragma("unroll") for (int ni = 0; ni < 2; ++ni)                                  \
          _Pragma("unroll") for (int kk = 0; kk < 2; ++kk)                              \
              acc[HA][HB][mi][ni] = __builtin_amdgcn_mfma_f32_16x16x32_bf16(            \
                  af[mi][kk], BF[ni][kk], acc[HA][HB][mi][ni], 0, 0, 0);                \
  __builtin_amdgcn_s_setprio(0);

  // prologue: stage K-tile 0 into buf0, full drain
  stage_chunk(0, 0, 0);
  stage_chunk(0, 1, 0);
  stage_chunk(0, 2, 0);
  stage_chunk(0, 3, 0);
  VMWAIT(0);
  RAW_BARRIER();

  for (int t = 0; t < NT - 1; ++t) {
    const int cb_ = (t & 1) * 65536, nb = ((t + 1) & 1) * 65536;
    const int k0n = (t + 1) * 64;
    // phase 0: quadrant (0,0)
    ldA(cb_, 0);
    ldB(bf0, cb_, 0);
    stage_chunk(nb, 0, k0n);
    RAW_BARRIER();
    MFMA16(0, 0, bf0);
    VMWAIT(4);
    RAW_BARRIER();
    // phase 1: quadrant (0,1) — reuse af
    ldB(bf1, cb_, 1);
    stage_chunk(nb, 1, k0n);
    RAW_BARRIER();
    MFMA16(0, 1, bf1);
    VMWAIT(4);
    RAW_BARRIER();
    // phase 2: quadrant (1,0) — reuse bf0
    ldA(cb_, 1);
    stage_chunk(nb, 2, k0n);
    RAW_BARRIER();
    MFMA16(1, 0, bf0);
    RAW_BARRIER();
    // phase 3: quadrant (1,1) — reuse af, bf1
    stage_chunk(nb, 3, k0n);
    RAW_BARRIER();
    MFMA16(1, 1, bf1);
    VMWAIT(4);
    RAW_BARRIER();
  }
  // final iteration (t = NT-1): no staging; entering with B1,A1 of last tile in flight
  {
    const int cb_ = ((NT - 1) & 1) * 65536;
    ldA(cb_, 0);
    ldB(bf0, cb_, 0);
    RAW_BARRIER();
    MFMA16(0, 0, bf0);
    VMWAIT(0);
    RAW_BARRIER();
    ldB(bf1, cb_, 1);
    RAW_BARRIER();
    MFMA16(0, 1, bf1);
    RAW_BARRIER();
    ldA(cb_, 1);
    RAW_BARRIER();
    MFMA16(1, 0, bf0);
    RAW_BARRIER();
    MFMA16(1, 1, bf1);
  }

  // ---- epilogue: route Q/K (with RoPE) and V^T ----
  const float rs = 0.127517436f;  // log2(e)/sqrt(128)
#pragma unroll
  for (int ha = 0; ha < 2; ++ha)
#pragma unroll
    for (int hb = 0; hb < 2; ++hb)
#pragma unroll
      for (int mi = 0; mi < 4; ++mi)
#pragma unroll
        for (int ni = 0; ni < 2; ++ni)
#pragma unroll
          for (int rr = 0; rr < 4; ++rr) {
            int gm = row0 + ha * 128 + wm * 64 + mi * 16 + ((lane >> 4) << 2) + rr;
            int gn = col0 + hb * 128 + wn * 32 + ni * 16 + (lane & 15);
            float v = acc[ha][hb][mi][ni][rr];
            int tsel = gn >> 11, nn = gn & 2047;
            int b = gm >> 11, s = gm & 2047, h = nn >> 7, hd = nn & 127;
            if (tsel < 2) {  // wave-uniform branch (gn>>11 constant per frag)
              float pv = __shfl_xor(v, 1, 64);
              float c = cbp[(s << 6) + (hd >> 1)];
              float sn = sbp[(s << 6) + (hd >> 1)];
              float o = (hd & 1) ? (pv * sn + v * c) : (v * c - pv * sn);
              if (tsel == 0) o *= rs;
              u16* dst = tsel ? k_ws : q_ws;
              dst[(size_t)((b << 4) | h) * 262144 + (s << 7) + hd] = f2bf(o);
            } else {
              vt_ws[(size_t)((b << 4) | h) * 262144 + (hd << 11) + s] = f2bf(v);
            }
          }
#undef MFMA16
}

// ---------------- GEMM (m97 structure): C[M=4096][N=2048] = A * B^T, f32 out ------
__global__ __launch_bounds__(256) void gemm_bt(const u16* __restrict__ A,
                                               const u16* __restrict__ Bw,
                                               float* __restrict__ C) {
  constexpr int K = 2048;
  __shared__ char sm[32768];  // A tile [128][64] @0, B tile [128][64] @16384, swizzled
  const int tid = threadIdx.x;
  const int lane = tid & 63;
  const int w = tid >> 6;
  const int by = blockIdx.x & 31;   // M/128 = 32
  const int bx = blockIdx.x >> 5;   // N/128 = 16
  const int row0 = by * 128, col0 = bx * 128;
  const int wr = (w >> 1) * 64, wc = (w & 1) * 64;
  f32x4 acc[4][4] = {};

  for (int k0 = 0; k0 < K; k0 += 64) {
    __syncthreads();
#pragma unroll
    for (int i = 0; i < 4; ++i) {
      int slot = tid + i * 256;
      int r = slot >> 3, s = slot & 7;
      int sl = s ^ (r & 7);
      async16(A + (size_t)(row0 + r) * K + (k0 + sl * 8), sm + slot * 16);
    }
#pragma unroll
    for (int i = 0; i < 4; ++i) {
      int slot = tid + i * 256;
      int r = slot >> 3, s = slot & 7;
      int sl = s ^ (r & 7);
      async16(Bw + (size_t)(col0 + r) * K + (k0 + sl * 8), sm + 16384 + slot * 16);
    }
    __syncthreads();
#pragma unroll
    for (int kk = 0; kk < 2; ++kk) {
      short8 af[4], bfr[4];
#pragma unroll
      for (int mi = 0; mi < 4; ++mi) {
        int r = wr + mi * 16 + (lane & 15);
        int ps = (kk * 4 + (lane >> 4)) ^ (r & 7);
        af[mi] = *reinterpret_cast<const short8*>(sm + r * 128 + ps * 16);
      }
#pragma unroll
      for (int ni = 0; ni < 4; ++ni) {
        int r = wc + ni * 16 + (lane & 15);
        int ps = (kk * 4 + (lane >> 4)) ^ (r & 7);
        bfr[ni] = *reinterpret_cast<const short8*>(sm + 16384 + r * 128 + ps * 16);
      }
#pragma unroll
      for (int mi = 0; mi < 4; ++mi)
#pragma unroll
        for (int ni = 0; ni < 4; ++ni)
          acc[mi][ni] = __builtin_amdgcn_mfma_f32_16x16x32_bf16(af[mi], bfr[ni], acc[mi][ni], 0, 0, 0);
    }
  }
#pragma unroll
  for (int mi = 0; mi < 4; ++mi)
#pragma unroll
    for (int ni = 0; ni < 4; ++ni)
#pragma unroll
      for (int r = 0; r < 4; ++r) {
        int gm = row0 + wr + mi * 16 + ((lane >> 4) << 2) + r;
        int gn = col0 + wc + ni * 16 + (lane & 15);
        C[((size_t)gm << 11) + gn] = acc[mi][ni][r];
      }
}

// ---------------- causal flash attention (32x32 MFMA, swapped QK^T) ----
// 512 blocks = 32 bh (XCD-clustered) x 16 q-tiles of 128 rows; 4 waves x 32 q-rows.
// qt decode pairs blocks (bid, bid+256) -> qt + qt' = 15 (balanced per-CU staged work).
// KVBLK=64 double-buffered (64KB LDS -> 2 blocks/CU). Swapped QK^T -> in-register
// softmax (shfl_xor 32 combine) + defer-max (T13); P packed via v_cvt_pk_bf16_f32 +
// shfl_xor half-exchange. PV computes O^T; epilogue transposes via LDS.
__global__ __launch_bounds__(256, 2) void attn_kernel(const u16* __restrict__ q_ws,
                                                      const u16* __restrict__ k_ws,
                                                      const u16* __restrict__ vt_ws,
                                                      u16* __restrict__ attn_ws) {
  constexpr int S = 2048;
  constexpr float NEGBIG = -3.0e38f;  // finite mask value: exp2 -> 0, no inf arithmetic
  // dbuf b @ b*32768: K[64 rows][16 slots sw] 16KB + Vt[128 rows][8 slots sw] 16KB
  __shared__ char sm[65536];
  const int tid = threadIdx.x, lane = tid & 63, w = tid >> 6;
  const int hi = lane >> 5, l31 = lane & 31;
  const int bid = blockIdx.x;
  const int qtr = bid >> 5;                           // 0..15
  const int qt = (qtr < 8) ? qtr : 23 - qtr;          // pair (bid,bid+256): qt+qt'=15
  const int bh = ((bid & 7) << 2) | ((bid >> 3) & 3); // same bh -> same XCD
  const int qr0 = qt * 128 + w * 32;
  const int ntile = 2 * qt + 2;       // staged kv tiles
  const int my_nt = (qr0 >> 6) + 1;   // wave-active kv tiles

  const u16* qp = q_ws + (size_t)bh * S * 128;
  const u16* kp = k_ws + (size_t)bh * S * 128;
  const u16* vp = vt_ws + (size_t)bh * 128 * S;

  // Q fragments (B-operand): col=lane&31=q, k=8*hi+e per 16-k step
  short8 qf[8];
  {
    const u16* qr = qp + (size_t)(qr0 + l31) * 128 + hi * 8;
#pragma unroll
    for (int ks = 0; ks < 8; ++ks) qf[ks] = *reinterpret_cast<const short8*>(qr + ks * 16);
  }
  f32x16 accO[4];
#pragma unroll
  for (int dc = 0; dc < 4; ++dc)
#pragma unroll
    for (int r = 0; r < 16; ++r) accO[dc][r] = 0.f;
  float m = -1e30f, l = 0.f;

  auto stage = [&](int bufoff, int kv0) {
#pragma unroll
    for (int i = 0; i < 4; ++i) {  // K: 64 rows x 16 slots, 4-bit XOR swizzle
      int slot = tid + i * 256;
      int r = slot >> 4, s = slot & 15;
      async16(kp + (size_t)(kv0 + r) * 128 + ((s ^ (r & 15)) * 8), sm + bufoff + slot * 16);
    }
#pragma unroll
    for (int i = 0; i < 4; ++i) {  // Vt: 128 rows x 8 slots, 3-bit XOR swizzle
      int slot = tid + i * 256;
      int r = slot >> 3, s = slot & 7;
      async16(vp + (size_t)r * S + kv0 + ((s ^ (r & 7)) * 8), sm + bufoff + 16384 + slot * 16);
    }
  };

  stage(0, 0);
  __syncthreads();

  for (int t = 0; t < ntile; ++t) {
    const char* kb = sm + (t & 1) * 32768;
    const char* vb = kb + 16384;
    if (t + 1 < ntile) stage(((t + 1) & 1) * 32768, (t + 1) * 64);

    if (t < my_nt) {
      // ---- QK^T swapped: sacc[jc][r] = S^T[j = 32jc+cr(r,hi)][q = qr0+l31] ----
      f32x16 sacc[2];
#pragma unroll
      for (int jc = 0; jc < 2; ++jc)
#pragma unroll
        for (int r = 0; r < 16; ++r) sacc[jc][r] = 0.f;
      __builtin_amdgcn_s_setprio(1);
#pragma unroll
      for (int jc = 0; jc < 2; ++jc) {
        const char* krp = kb + (jc * 32 + l31) * 256;
        const int sw = l31 & 15;
#pragma unroll
        for (int ks = 0; ks < 8; ++ks) {
          short8 kf = *reinterpret_cast<const short8*>(krp + (((2 * ks + hi) ^ sw) << 4));
          sacc[jc] = __builtin_amdgcn_mfma_f32_32x32x16_bf16(kf, qf[ks], sacc[jc], 0, 0, 0);
        }
      }
      __builtin_amdgcn_s_setprio(0);
      // ---- causal mask (only the diagonal tile) ----
      if (t == my_nt - 1) {
#pragma unroll
        for (int jc = 0; jc < 2; ++jc) {
          int thr = qr0 + l31 - t * 64 - 32 * jc - 4 * hi;
#pragma unroll
          for (int r = 0; r < 16; ++r) {
            int c0 = (r & 3) + 8 * (r >> 2);
            if (c0 > thr) sacc[jc][r] = NEGBIG;
          }
        }
      }
      // ---- in-register online softmax; defer-max (T13) ----
      float pmA = NEGBIG, pmB = NEGBIG, pmC = NEGBIG, pmD = NEGBIG;
#pragma unroll
      for (int jc = 0; jc < 2; ++jc)
#pragma unroll
        for (int r = 0; r < 16; r += 4) {
          pmA = fmaxf(pmA, sacc[jc][r]);
          pmB = fmaxf(pmB, sacc[jc][r + 1]);
          pmC = fmaxf(pmC, sacc[jc][r + 2]);
          pmD = fmaxf(pmD, sacc[jc][r + 3]);
        }
      float pmax = fmaxf(fmaxf(pmA, pmB), fmaxf(pmC, pmD));
      pmax = fmaxf(pmax, __shfl_xor(pmax, 32, 64));
      if (!__all(pmax - m <= 8.0f)) {  // rescale path (wave-uniform)
        float mnew = fmaxf(m, pmax);
        float scl = exp2f(m - mnew);
        m = mnew;
        l *= scl;
#pragma unroll
        for (int dc = 0; dc < 4; ++dc)
#pragma unroll
          for (int r = 0; r < 16; ++r) accO[dc][r] *= scl;
      }
      float sA = 0.f, sB = 0.f, sC = 0.f, sD = 0.f;
#pragma unroll
      for (int jc = 0; jc < 2; ++jc)
#pragma unroll
        for (int r = 0; r < 16; r += 4) {
          float p0 = exp2f(sacc[jc][r] - m);
          float p1 = exp2f(sacc[jc][r + 1] - m);
          float p2 = exp2f(sacc[jc][r + 2] - m);
          float p3 = exp2f(sacc[jc][r + 3] - m);
          sacc[jc][r] = p0; sacc[jc][r + 1] = p1; sacc[jc][r + 2] = p2; sacc[jc][r + 3] = p3;
          sA += p0; sB += p1; sC += p2; sD += p3;
        }
      float ps = (sA + sB) + (sC + sD);
      ps += __shfl_xor(ps, 32, 64);
      l += ps;
      // ---- pack P -> bf16 B-fragments (cvt_pk + shfl_xor half-exchange) ----
      short8 pfrag[4];
#pragma unroll
      for (int ks = 0; ks < 4; ++ks) {
        const int jc = ks >> 1, u8 = (ks & 1) * 8;
        u32 wA = cvtpk(sacc[jc][u8 + 0], sacc[jc][u8 + 1]);
        u32 wB = cvtpk(sacc[jc][u8 + 2], sacc[jc][u8 + 3]);
        u32 wC = cvtpk(sacc[jc][u8 + 4], sacc[jc][u8 + 5]);
        u32 wD = cvtpk(sacc[jc][u8 + 6], sacc[jc][u8 + 7]);
        u32 qA = __shfl_xor(wA, 32, 64);
        u32 qB = __shfl_xor(wB, 32, 64);
        u32 qC = __shfl_xor(wC, 32, 64);
        u32 qD = __shfl_xor(wD, 32, 64);
        u32x4 t4;
        t4.x = hi ? qC : wA;
        t4.y = hi ? qD : wB;
        t4.z = hi ? wC : qA;
        t4.w = hi ? wD : qB;
        pfrag[ks] = __builtin_bit_cast(short8, t4);
      }
      // ---- PV: accO[dc][r] = O^T[d = 32dc+cr(r,hi)][q = qr0+l31] ----
      __builtin_amdgcn_s_setprio(1);
#pragma unroll
      for (int ks = 0; ks < 4; ++ks) {
#pragma unroll
        for (int dc = 0; dc < 4; ++dc) {
          const char* vrp = vb + (dc * 32 + l31) * 128;
          short8 vf = *reinterpret_cast<const short8*>(vrp + (((2 * ks + hi) ^ (l31 & 7)) << 4));
          accO[dc] = __builtin_amdgcn_mfma_f32_32x32x16_bf16(vf, pfrag[ks], accO[dc], 0, 0, 0);
        }
      }
      __builtin_amdgcn_s_setprio(0);
    }
    __syncthreads();  // drains vmcnt (prefetch landed) + protects dbuf reuse
  }

  // ---- epilogue: O^T -> LDS (swizzled) -> coalesced bf16 rows of attn_ws [B,S,D] ----
  const int b = bh >> 4, h = bh & 15;
  char* tb = sm + w * 8192;  // per-wave [32 q][128 d] bf16 tile
  float inv = (l > 0.f) ? 1.0f / l : 0.f;
#pragma unroll
  for (int dc = 0; dc < 4; ++dc)
#pragma unroll
    for (int r = 0; r < 16; ++r) {
      int d = dc * 32 + (r & 3) + 8 * (r >> 2) + 4 * hi;
      int byte = l31 * 256 + d * 2;
      *reinterpret_cast<u16*>(tb + (byte ^ ((l31 & 7) << 4))) = f2bf(accO[dc][r] * inv);
    }
  asm volatile("s_waitcnt lgkmcnt(0)" ::: "memory");
#pragma unroll
  for (int i = 0; i < 8; ++i) {
    int r = i * 4 + (lane >> 4);
    int s = lane & 15;
    f32x4 v = *reinterpret_cast<const f32x4*>(tb + r * 256 + ((s ^ (r & 7)) << 4));
    size_t addr = ((size_t)(b * 2048 + qr0 + r) << 11) + (h << 7) + s * 8;
    *reinterpret_cast<f32x4*>(attn_ws + addr) = v;
  }
}

extern "C" void kernel_launch(void* const* d_in, const int* in_sizes, int n_in,
                              void* d_out, int out_size, void* d_ws, size_t ws_size,
                              hipStream_t stream) {
  const float* x = (const float*)d_in[0];
  // d_in[1] = start_pos (0), d_in[4] = mask (causal) — handled analytically
  const float* cb = (const float*)d_in[2];
  const float* sb = (const float*)d_in[3];
  const float* wq = (const float*)d_in[5];
  const float* wk = (const float*)d_in[6];
  const float* wv = (const float*)d_in[7];
  const float* wo = (const float*)d_in[8];

  char* p = (char*)d_ws;
  u16* xb  = (u16*)p; p += (size_t)4096 * 2048 * 2;
  u16* wqb = (u16*)p; p += (size_t)2048 * 2048 * 2;  // wq,wk,wv,wo contiguous ->
  u16* wkb = (u16*)p; p += (size_t)2048 * 2048 * 2;  // fused QKV B = wqb[0..6144)
  u16* wvb = (u16*)p; p += (size_t)2048 * 2048 * 2;
  u16* wob = (u16*)p; p += (size_t)2048 * 2048 * 2;
  u16* q_ws = (u16*)p; p += (size_t)4096 * 2048 * 2;
  u16* k_ws = (u16*)p; p += (size_t)4096 * 2048 * 2;
  u16* vt_ws = (u16*)p; p += (size_t)4096 * 2048 * 2;
  u16* attn_ws = xb;  // xb is dead after the QKV projection; reuse it
  (void)wkb; (void)wvb;

  cast_all_kernel<<<3072, 256, 0, stream>>>(x, wq, wk, wv, wo, xb);

  gemm_qkv8<<<384, 512, 0, stream>>>(xb, wqb, q_ws, k_ws, vt_ws, cb, sb);

  attn_kernel<<<512, 256, 0, stream>>>(q_ws, k_ws, vt_ws, attn_ws);

  gemm_bt<<<512, 256, 0, stream>>>(attn_ws, wob, (float*)d_out);
}

// Round 8
// 293.865 us; speedup vs baseline: 1.0097x; 1.0097x over previous
//
#include <hip/hip_runtime.h>

typedef __attribute__((ext_vector_type(8))) short short8;
typedef __attribute__((ext_vector_type(4))) float f32x4;
typedef __attribute__((ext_vector_type(16))) float f32x16;
typedef unsigned int u32;
typedef __attribute__((ext_vector_type(4))) u32 u32x4;
typedef unsigned short u16;

#define DEV __device__ __forceinline__

DEV void async16(const void* g, void* l) {
  __builtin_amdgcn_global_load_lds((const __attribute__((address_space(1))) u32*)g,
                                   (__attribute__((address_space(3))) u32*)l, 16, 0, 0);
}

DEV u16 f2bf(float f) {
  u32 u = __builtin_bit_cast(u32, f);
  u32 r = (u + 0x7FFFu + ((u >> 16) & 1u)) >> 16;
  return (u16)r;
}
DEV float bf2f(u16 h) { return __builtin_bit_cast(float, (u32)h << 16); }

DEV u32 cvtpk(float lo, float hi) {  // packs {bf16(lo), bf16(hi)} -> u32 (lo in low16)
  u32 r;
  asm("v_cvt_pk_bf16_f32 %0, %1, %2" : "=v"(r) : "v"(lo), "v"(hi));
  return r;
}

#define RAW_BARRIER() asm volatile("s_barrier" ::: "memory")
#define VMWAIT(N) asm volatile("s_waitcnt vmcnt(" #N ")" ::: "memory")

// ---------------- fused cast f32 -> bf16 of x + 4 weights (dst regions contiguous) --
__global__ void cast_all_kernel(const float* __restrict__ x, const float* __restrict__ wq,
                                const float* __restrict__ wk, const float* __restrict__ wv,
                                const float* __restrict__ wo, u16* __restrict__ out) {
  constexpr int XN = 2097152;  // x float4 count (4096*2048/4)
  constexpr int WN = 1048576;  // each weight float4 count
  constexpr int TOT = XN + 4 * WN;
  int stride = gridDim.x * blockDim.x;
  for (int i = blockIdx.x * blockDim.x + threadIdx.x; i < TOT; i += stride) {
    const float* src;
    int off;
    if (i < XN) {
      src = x; off = i;
    } else {
      int j = i - XN, wsel = j >> 20;
      const float* ws4[4] = {wq, wk, wv, wo};
      src = ws4[wsel]; off = j & (WN - 1);
    }
    float4 v = reinterpret_cast<const float4*>(src)[off];
    ushort4 o = make_ushort4(f2bf(v.x), f2bf(v.y), f2bf(v.z), f2bf(v.w));
    reinterpret_cast<ushort4*>(out)[i] = o;
  }
}

// ---------------- 256^2 fused QKV GEMM, m201-style deep pipeline (+RoPE epilogue) ---
// C[M=4096][N=6144] = A[M][K=2048] * B[N][K]^T, bf16 in, f32 acc.
// 384 blocks x 512 thr (8 waves: wm=w>>2 2 M-halves, wn=w&3 4 N-strips).
// Iteration = 2 K-tiles (buf0=even, buf1=odd; 8 chunk-slots of 16KB). 6 phases/iter:
// {vmcnt(8); s_barrier; ds_reads; stage 1-2 chunks; setprio MFMA}. Chunks recycled
// per-slot: staged >=2 phases after last read, waited 5-6 phases after issue —
// vmcnt never drains a load younger than 4 phases (m201's counted-vmcnt property).
// 2-D XCD swizzle: each XCD owns 8Mx6N tile block (14.6 MB fetch/XCD).
// Epilogue: Q/K RoPE via lane^1 shfl (f32), Q scaled log2e/sqrt(128);
// Q/K -> [B,H,S,HD], V -> [B,H,HD,S].
__global__ __launch_bounds__(512, 2) void gemm_qkv8(const u16* __restrict__ A,
                                                    const u16* __restrict__ Bw,
                                                    u16* __restrict__ q_ws,
                                                    u16* __restrict__ k_ws,
                                                    u16* __restrict__ vt_ws,
                                                    const float* __restrict__ cbp,
                                                    const float* __restrict__ sbp) {
  constexpr int K = 2048, NITER = 16;  // 32 K-tiles, 2 per iteration
  // slots (16KB each): buf0: A0@0 A1@16384 B0@32768 B1@49152 ; buf1: +65536
  __shared__ char sm[131072];
  const int tid = threadIdx.x, lane = tid & 63, w = tid >> 6;
  const int wm = w >> 2, wn = w & 3;
  const int bid = blockIdx.x;
  const int xcd = bid & 7, jj = bid >> 3;          // 48 blocks per XCD
  const int mt = (xcd & 1) * 8 + (jj & 7);         // 16 M-tiles
  const int ntc = (xcd >> 1) * 6 + (jj >> 3);      // 24 N-tiles
  const int row0 = mt * 256, col0 = ntc * 256;

  f32x4 acc[2][2][4][2] = {};

  auto stage = [&](int slotbase, const u16* src, int rbase, int k0) {
#pragma unroll
    for (int i = 0; i < 2; ++i) {
      int slot = tid + i * 512;
      int r = slot >> 3, cs = slot & 7;
      async16(src + (size_t)(rbase + r) * K + k0 + ((cs ^ (r & 7)) << 3),
              sm + slotbase + slot * 16);
    }
  };

  short8 af[4][2], bf0[2][2], bf1[2][2];
  auto ldA = [&](int slotbase) {
#pragma unroll
    for (int mi = 0; mi < 4; ++mi) {
      int row = wm * 64 + mi * 16 + (lane & 15);
#pragma unroll
      for (int kk = 0; kk < 2; ++kk)
        af[mi][kk] = *reinterpret_cast<const short8*>(
            sm + slotbase + row * 128 + ((((kk << 2) + (lane >> 4)) ^ (row & 7)) << 4));
    }
  };
  auto ldB = [&](short8 (&bf)[2][2], int slotbase) {
#pragma unroll
    for (int ni = 0; ni < 2; ++ni) {
      int row = wn * 32 + ni * 16 + (lane & 15);
#pragma unroll
      for (int kk = 0; kk < 2; ++kk)
        bf[ni][kk] = *reinterpret_cast<const short8*>(
            sm + slotbase + row * 128 + ((((kk << 2) + (lane >> 4)) ^ (row & 7)) << 4));
    }
  };

#define MFMA16(HA, HB, BF)                                                              \
  __builtin_amdgcn_s_setprio(1);                                                        \
  _Pragma("unroll") for (int mi = 0; mi < 4; ++mi)                                      \
      _Pragma("unroll") for (int ni = 0; ni < 2; ++ni)                                  \
          _Pragma("unroll") for (int kk = 0; kk < 2; ++kk)                              \
              acc[HA][HB][mi][ni] = __builtin_amdgcn_mfma_f32_16x16x32_bf16(            \
                  af[mi][kk], BF[ni][kk], acc[HA][HB][mi][ni], 0, 0, 0);                \
  __builtin_amdgcn_s_setprio(0);

  // prologue (mimics steady-state tail): T0=tile0 all 4 chunks, T1=tile1 A0,B0
  stage(0, A, row0, 0);
  stage(32768, Bw, col0, 0);
  stage(49152, Bw, col0 + 128, 0);
  stage(16384, A, row0 + 128, 0);
  stage(65536, A, row0, 64);
  stage(65536 + 32768, Bw, col0, 64);

  for (int i = 0; i < NITER - 1; ++i) {
    const int kT1 = i * 128 + 64, kN = (i + 1) * 128;
    // P1: buf0 quadrant (0,0)
    VMWAIT(8); RAW_BARRIER();
    ldA(0); ldB(bf0, 32768);
    stage(65536 + 49152, Bw, col0 + 128, kT1);  // b1.B1 <- odd tile
    MFMA16(0, 0, bf0);
    // P2: buf0 (0,1)
    VMWAIT(8); RAW_BARRIER();
    ldB(bf1, 49152);
    stage(65536 + 16384, A, row0 + 128, kT1);   // b1.A1 <- odd tile
    MFMA16(0, 1, bf1);
    // P3+4: buf0 (1,0),(1,1)
    VMWAIT(8); RAW_BARRIER();
    ldA(16384);
    stage(0, A, row0, kN);                       // b0.A0 <- even tile+2
    stage(32768, Bw, col0, kN);                  // b0.B0
    MFMA16(1, 0, bf0);
    MFMA16(1, 1, bf1);
    // P5: buf1 (0,0)
    VMWAIT(8); RAW_BARRIER();
    ldA(65536); ldB(bf0, 65536 + 32768);
    stage(49152, Bw, col0 + 128, kN);            // b0.B1
    MFMA16(0, 0, bf0);
    // P6: buf1 (0,1)
    VMWAIT(8); RAW_BARRIER();
    ldB(bf1, 65536 + 49152);
    stage(16384, A, row0 + 128, kN);             // b0.A1
    MFMA16(0, 1, bf1);
    // P7+8: buf1 (1,0),(1,1)
    VMWAIT(8); RAW_BARRIER();
    ldA(65536 + 16384);
    stage(65536, A, row0, kN + 64);              // b1.A0 <- odd tile+2
    stage(65536 + 32768, Bw, col0, kN + 64);     // b1.B0
    MFMA16(1, 0, bf0);
    MFMA16(1, 1, bf1);
  }
  // final iteration (tiles 30,31): drain ledger 8,8,8 / 4,2,0
  {
    const int kT1 = (NITER - 1) * 128 + 64;
    VMWAIT(8); RAW_BARRIER();
    ldA(0); ldB(bf0, 32768);
    stage(65536 + 49152, Bw, col0 + 128, kT1);
    MFMA16(0, 0, bf0);
    VMWAIT(8); RAW_BARRIER();
    ldB(bf1, 49152);
    stage(65536 + 16384, A, row0 + 128, kT1);
    MFMA16(0, 1, bf1);
    VMWAIT(8); RAW_BARRIER();
    ldA(16384);
    MFMA16(1, 0, bf0);
    MFMA16(1, 1, bf1);
    VMWAIT(4); RAW_BARRIER();
    ldA(65536); ldB(bf0, 65536 + 32768);
    MFMA16(0, 0, bf0);
    VMWAIT(2); RAW_BARRIER();
    ldB(bf1, 65536 + 49152);
    MFMA16(0, 1, bf1);
    VMWAIT(0); RAW_BARRIER();
    ldA(65536 + 16384);
    MFMA16(1, 0, bf0);
    MFMA16(1, 1, bf1);
  }

  // ---- epilogue: route Q/K (with RoPE) and V^T ----
  const float rs = 0.127517436f;  // log2(e)/sqrt(128)
#pragma unroll
  for (int ha = 0; ha < 2; ++ha)
#pragma unroll
    for (int hb = 0; hb < 2; ++hb)
#pragma unroll
      for (int mi = 0; mi < 4; ++mi)
#pragma unroll
        for (int ni = 0; ni < 2; ++ni)
#pragma unroll
          for (int rr = 0; rr < 4; ++rr) {
            int gm = row0 + ha * 128 + wm * 64 + mi * 16 + ((lane >> 4) << 2) + rr;
            int gn = col0 + hb * 128 + wn * 32 + ni * 16 + (lane & 15);
            float v = acc[ha][hb][mi][ni][rr];
            int tsel = gn >> 11, nn = gn & 2047;
            int b = gm >> 11, s = gm & 2047, h = nn >> 7, hd = nn & 127;
            if (tsel < 2) {  // wave-uniform branch (gn>>11 constant per frag)
              float pv = __shfl_xor(v, 1, 64);
              float c = cbp[(s << 6) + (hd >> 1)];
              float sn = sbp[(s << 6) + (hd >> 1)];
              float o = (hd & 1) ? (pv * sn + v * c) : (v * c - pv * sn);
              if (tsel == 0) o *= rs;
              u16* dst = tsel ? k_ws : q_ws;
              dst[(size_t)((b << 4) | h) * 262144 + (s << 7) + hd] = f2bf(o);
            } else {
              vt_ws[(size_t)((b << 4) | h) * 262144 + (hd << 11) + s] = f2bf(v);
            }
          }
#undef MFMA16
}

// ---------------- GEMM (m97 structure): C[M=4096][N=2048] = A * B^T, f32 out ------
__global__ __launch_bounds__(256) void gemm_bt(const u16* __restrict__ A,
                                               const u16* __restrict__ Bw,
                                               float* __restrict__ C) {
  constexpr int K = 2048;
  __shared__ char sm[32768];  // A tile [128][64] @0, B tile [128][64] @16384, swizzled
  const int tid = threadIdx.x;
  const int lane = tid & 63;
  const int w = tid >> 6;
  const int by = blockIdx.x & 31;   // M/128 = 32
  const int bx = blockIdx.x >> 5;   // N/128 = 16
  const int row0 = by * 128, col0 = bx * 128;
  const int wr = (w >> 1) * 64, wc = (w & 1) * 64;
  f32x4 acc[4][4] = {};

  for (int k0 = 0; k0 < K; k0 += 64) {
    __syncthreads();
#pragma unroll
    for (int i = 0; i < 4; ++i) {
      int slot = tid + i * 256;
      int r = slot >> 3, s = slot & 7;
      int sl = s ^ (r & 7);
      async16(A + (size_t)(row0 + r) * K + (k0 + sl * 8), sm + slot * 16);
    }
#pragma unroll
    for (int i = 0; i < 4; ++i) {
      int slot = tid + i * 256;
      int r = slot >> 3, s = slot & 7;
      int sl = s ^ (r & 7);
      async16(Bw + (size_t)(col0 + r) * K + (k0 + sl * 8), sm + 16384 + slot * 16);
    }
    __syncthreads();
#pragma unroll
    for (int kk = 0; kk < 2; ++kk) {
      short8 af[4], bfr[4];
#pragma unroll
      for (int mi = 0; mi < 4; ++mi) {
        int r = wr + mi * 16 + (lane & 15);
        int ps = (kk * 4 + (lane >> 4)) ^ (r & 7);
        af[mi] = *reinterpret_cast<const short8*>(sm + r * 128 + ps * 16);
      }
#pragma unroll
      for (int ni = 0; ni < 4; ++ni) {
        int r = wc + ni * 16 + (lane & 15);
        int ps = (kk * 4 + (lane >> 4)) ^ (r & 7);
        bfr[ni] = *reinterpret_cast<const short8*>(sm + 16384 + r * 128 + ps * 16);
      }
#pragma unroll
      for (int mi = 0; mi < 4; ++mi)
#pragma unroll
        for (int ni = 0; ni < 4; ++ni)
          acc[mi][ni] = __builtin_amdgcn_mfma_f32_16x16x32_bf16(af[mi], bfr[ni], acc[mi][ni], 0, 0, 0);
    }
  }
#pragma unroll
  for (int mi = 0; mi < 4; ++mi)
#pragma unroll
    for (int ni = 0; ni < 4; ++ni)
#pragma unroll
      for (int r = 0; r < 4; ++r) {
        int gm = row0 + wr + mi * 16 + ((lane >> 4) << 2) + r;
        int gn = col0 + wc + ni * 16 + (lane & 15);
        C[((size_t)gm << 11) + gn] = acc[mi][ni][r];
      }
}

// ---------------- causal flash attention (32x32 MFMA, swapped QK^T) ----
// 512 blocks = 32 bh (XCD-clustered) x 16 q-tiles of 128 rows; 4 waves x 32 q-rows.
// qt decode pairs blocks (bid, bid+256) -> qt + qt' = 15 (balanced per-CU staged work).
// KVBLK=64 double-buffered (64KB LDS -> 2 blocks/CU). Swapped QK^T -> in-register
// softmax (shfl_xor 32 combine) + defer-max (T13); P packed via v_cvt_pk_bf16_f32 +
// shfl_xor half-exchange. PV computes O^T; epilogue transposes via LDS.
__global__ __launch_bounds__(256, 2) void attn_kernel(const u16* __restrict__ q_ws,
                                                      const u16* __restrict__ k_ws,
                                                      const u16* __restrict__ vt_ws,
                                                      u16* __restrict__ attn_ws) {
  constexpr int S = 2048;
  constexpr float NEGBIG = -3.0e38f;  // finite mask value: exp2 -> 0, no inf arithmetic
  // dbuf b @ b*32768: K[64 rows][16 slots sw] 16KB + Vt[128 rows][8 slots sw] 16KB
  __shared__ char sm[65536];
  const int tid = threadIdx.x, lane = tid & 63, w = tid >> 6;
  const int hi = lane >> 5, l31 = lane & 31;
  const int bid = blockIdx.x;
  const int qtr = bid >> 5;                           // 0..15
  const int qt = (qtr < 8) ? qtr : 23 - qtr;          // pair (bid,bid+256): qt+qt'=15
  const int bh = ((bid & 7) << 2) | ((bid >> 3) & 3); // same bh -> same XCD
  const int qr0 = qt * 128 + w * 32;
  const int ntile = 2 * qt + 2;       // staged kv tiles
  const int my_nt = (qr0 >> 6) + 1;   // wave-active kv tiles

  const u16* qp = q_ws + (size_t)bh * S * 128;
  const u16* kp = k_ws + (size_t)bh * S * 128;
  const u16* vp = vt_ws + (size_t)bh * 128 * S;

  // Q fragments (B-operand): col=lane&31=q, k=8*hi+e per 16-k step
  short8 qf[8];
  {
    const u16* qr = qp + (size_t)(qr0 + l31) * 128 + hi * 8;
#pragma unroll
    for (int ks = 0; ks < 8; ++ks) qf[ks] = *reinterpret_cast<const short8*>(qr + ks * 16);
  }
  f32x16 accO[4];
#pragma unroll
  for (int dc = 0; dc < 4; ++dc)
#pragma unroll
    for (int r = 0; r < 16; ++r) accO[dc][r] = 0.f;
  float m = -1e30f, l = 0.f;

  auto stage = [&](int bufoff, int kv0) {
#pragma unroll
    for (int i = 0; i < 4; ++i) {  // K: 64 rows x 16 slots, 4-bit XOR swizzle
      int slot = tid + i * 256;
      int r = slot >> 4, s = slot & 15;
      async16(kp + (size_t)(kv0 + r) * 128 + ((s ^ (r & 15)) * 8), sm + bufoff + slot * 16);
    }
#pragma unroll
    for (int i = 0; i < 4; ++i) {  // Vt: 128 rows x 8 slots, 3-bit XOR swizzle
      int slot = tid + i * 256;
      int r = slot >> 3, s = slot & 7;
      async16(vp + (size_t)r * S + kv0 + ((s ^ (r & 7)) * 8), sm + bufoff + 16384 + slot * 16);
    }
  };

  stage(0, 0);
  __syncthreads();

  for (int t = 0; t < ntile; ++t) {
    const char* kb = sm + (t & 1) * 32768;
    const char* vb = kb + 16384;
    if (t + 1 < ntile) stage(((t + 1) & 1) * 32768, (t + 1) * 64);

    if (t < my_nt) {
      // ---- QK^T swapped: sacc[jc][r] = S^T[j = 32jc+cr(r,hi)][q = qr0+l31] ----
      f32x16 sacc[2];
#pragma unroll
      for (int jc = 0; jc < 2; ++jc)
#pragma unroll
        for (int r = 0; r < 16; ++r) sacc[jc][r] = 0.f;
      __builtin_amdgcn_s_setprio(1);
#pragma unroll
      for (int jc = 0; jc < 2; ++jc) {
        const char* krp = kb + (jc * 32 + l31) * 256;
        const int sw = l31 & 15;
#pragma unroll
        for (int ks = 0; ks < 8; ++ks) {
          short8 kf = *reinterpret_cast<const short8*>(krp + (((2 * ks + hi) ^ sw) << 4));
          sacc[jc] = __builtin_amdgcn_mfma_f32_32x32x16_bf16(kf, qf[ks], sacc[jc], 0, 0, 0);
        }
      }
      __builtin_amdgcn_s_setprio(0);
      // ---- causal mask (only the diagonal tile) ----
      if (t == my_nt - 1) {
#pragma unroll
        for (int jc = 0; jc < 2; ++jc) {
          int thr = qr0 + l31 - t * 64 - 32 * jc - 4 * hi;
#pragma unroll
          for (int r = 0; r < 16; ++r) {
            int c0 = (r & 3) + 8 * (r >> 2);
            if (c0 > thr) sacc[jc][r] = NEGBIG;
          }
        }
      }
      // ---- in-register online softmax; defer-max (T13) ----
      float pmA = NEGBIG, pmB = NEGBIG, pmC = NEGBIG, pmD = NEGBIG;
#pragma unroll
      for (int jc = 0; jc < 2; ++jc)
#pragma unroll
        for (int r = 0; r < 16; r += 4) {
          pmA = fmaxf(pmA, sacc[jc][r]);
          pmB = fmaxf(pmB, sacc[jc][r + 1]);
          pmC = fmaxf(pmC, sacc[jc][r + 2]);
          pmD = fmaxf(pmD, sacc[jc][r + 3]);
        }
      float pmax = fmaxf(fmaxf(pmA, pmB), fmaxf(pmC, pmD));
      pmax = fmaxf(pmax, __shfl_xor(pmax, 32, 64));
      if (!__all(pmax - m <= 8.0f)) {  // rescale path (wave-uniform)
        float mnew = fmaxf(m, pmax);
        float scl = exp2f(m - mnew);
        m = mnew;
        l *= scl;
#pragma unroll
        for (int dc = 0; dc < 4; ++dc)
#pragma unroll
          for (int r = 0; r < 16; ++r) accO[dc][r] *= scl;
      }
      float sA = 0.f, sB = 0.f, sC = 0.f, sD = 0.f;
#pragma unroll
      for (int jc = 0; jc < 2; ++jc)
#pragma unroll
        for (int r = 0; r < 16; r += 4) {
          float p0 = exp2f(sacc[jc][r] - m);
          float p1 = exp2f(sacc[jc][r + 1] - m);
          float p2 = exp2f(sacc[jc][r + 2] - m);
          float p3 = exp2f(sacc[jc][r + 3] - m);
          sacc[jc][r] = p0; sacc[jc][r + 1] = p1; sacc[jc][r + 2] = p2; sacc[jc][r + 3] = p3;
          sA += p0; sB += p1; sC += p2; sD += p3;
        }
      float ps = (sA + sB) + (sC + sD);
      ps += __shfl_xor(ps, 32, 64);
      l += ps;
      // ---- pack P -> bf16 B-fragments (cvt_pk + shfl_xor half-exchange) ----
      short8 pfrag[4];
#pragma unroll
      for (int ks = 0; ks < 4; ++ks) {
        const int jc = ks >> 1, u8 = (ks & 1) * 8;
        u32 wA = cvtpk(sacc[jc][u8 + 0], sacc[jc][u8 + 1]);
        u32 wB = cvtpk(sacc[jc][u8 + 2], sacc[jc][u8 + 3]);
        u32 wC = cvtpk(sacc[jc][u8 + 4], sacc[jc][u8 + 5]);
        u32 wD = cvtpk(sacc[jc][u8 + 6], sacc[jc][u8 + 7]);
        u32 qA = __shfl_xor(wA, 32, 64);
        u32 qB = __shfl_xor(wB, 32, 64);
        u32 qC = __shfl_xor(wC, 32, 64);
        u32 qD = __shfl_xor(wD, 32, 64);
        u32x4 t4;
        t4.x = hi ? qC : wA;
        t4.y = hi ? qD : wB;
        t4.z = hi ? wC : qA;
        t4.w = hi ? wD : qB;
        pfrag[ks] = __builtin_bit_cast(short8, t4);
      }
      // ---- PV: accO[dc][r] = O^T[d = 32dc+cr(r,hi)][q = qr0+l31] ----
      __builtin_amdgcn_s_setprio(1);
#pragma unroll
      for (int ks = 0; ks < 4; ++ks) {
#pragma unroll
        for (int dc = 0; dc < 4; ++dc) {
          const char* vrp = vb + (dc * 32 + l31) * 128;
          short8 vf = *reinterpret_cast<const short8*>(vrp + (((2 * ks + hi) ^ (l31 & 7)) << 4));
          accO[dc] = __builtin_amdgcn_mfma_f32_32x32x16_bf16(vf, pfrag[ks], accO[dc], 0, 0, 0);
        }
      }
      __builtin_amdgcn_s_setprio(0);
    }
    __syncthreads();  // drains vmcnt (prefetch landed) + protects dbuf reuse
  }

  // ---- epilogue: O^T -> LDS (swizzled) -> coalesced bf16 rows of attn_ws [B,S,D] ----
  const int b = bh >> 4, h = bh & 15;
  char* tb = sm + w * 8192;  // per-wave [32 q][128 d] bf16 tile
  float inv = (l > 0.f) ? 1.0f / l : 0.f;
#pragma unroll
  for (int dc = 0; dc < 4; ++dc)
#pragma unroll
    for (int r = 0; r < 16; ++r) {
      int d = dc * 32 + (r & 3) + 8 * (r >> 2) + 4 * hi;
      int byte = l31 * 256 + d * 2;
      *reinterpret_cast<u16*>(tb + (byte ^ ((l31 & 7) << 4))) = f2bf(accO[dc][r] * inv);
    }
  asm volatile("s_waitcnt lgkmcnt(0)" ::: "memory");
#pragma unroll
  for (int i = 0; i < 8; ++i) {
    int r = i * 4 + (lane >> 4);
    int s = lane & 15;
    f32x4 v = *reinterpret_cast<const f32x4*>(tb + r * 256 + ((s ^ (r & 7)) << 4));
    size_t addr = ((size_t)(b * 2048 + qr0 + r) << 11) + (h << 7) + s * 8;
    *reinterpret_cast<f32x4*>(attn_ws + addr) = v;
  }
}

extern "C" void kernel_launch(void* const* d_in, const int* in_sizes, int n_in,
                              void* d_out, int out_size, void* d_ws, size_t ws_size,
                              hipStream_t stream) {
  const float* x = (const float*)d_in[0];
  // d_in[1] = start_pos (0), d_in[4] = mask (causal) — handled analytically
  const float* cb = (const float*)d_in[2];
  const float* sb = (const float*)d_in[3];
  const float* wq = (const float*)d_in[5];
  const float* wk = (const float*)d_in[6];
  const float* wv = (const float*)d_in[7];
  const float* wo = (const float*)d_in[8];

  char* p = (char*)d_ws;
  u16* xb  = (u16*)p; p += (size_t)4096 * 2048 * 2;
  u16* wqb = (u16*)p; p += (size_t)2048 * 2048 * 2;  // wq,wk,wv,wo contiguous ->
  u16* wkb = (u16*)p; p += (size_t)2048 * 2048 * 2;  // fused QKV B = wqb[0..6144)
  u16* wvb = (u16*)p; p += (size_t)2048 * 2048 * 2;
  u16* wob = (u16*)p; p += (size_t)2048 * 2048 * 2;
  u16* q_ws = (u16*)p; p += (size_t)4096 * 2048 * 2;
  u16* k_ws = (u16*)p; p += (size_t)4096 * 2048 * 2;
  u16* vt_ws = (u16*)p; p += (size_t)4096 * 2048 * 2;
  u16* attn_ws = xb;  // xb is dead after the QKV projection; reuse it
  (void)wkb; (void)wvb;

  cast_all_kernel<<<3072, 256, 0, stream>>>(x, wq, wk, wv, wo, xb);

  gemm_qkv8<<<384, 512, 0, stream>>>(xb, wqb, q_ws, k_ws, vt_ws, cb, sb);

  attn_kernel<<<512, 256, 0, stream>>>(q_ws, k_ws, vt_ws, attn_ws);

  gemm_bt<<<512, 256, 0, stream>>>(attn_ws, wob, (float*)d_out);
}